// Round 9
// baseline (202.195 us; speedup 1.0000x reference)
//
#include <hip/hip_runtime.h>
#include <hip/hip_bf16.h>

#define B_ 128
#define S_ 196
#define E_ 768
#define M_ 768
#define KTOT (S_*E_)            // 150528
#define BK 128                  // k per superstep
#define SS_TOTAL (KTOT/BK)      // 1176
#define KSPLIT 42
#define SS_PER (SS_TOTAL/KSPLIT) // 28
#define BN 48                   // m-rows per workgroup
#define MTN (M_/BN)             // 16
#define PITCH 272               // LDS row pitch bytes (256 + 16 pad -> ~2-way banks)
#define ZC 6                    // z-chunks in reduce kernel

typedef __bf16 bf16x8 __attribute__((ext_vector_type(8)));
typedef __bf16 bf16x2 __attribute__((ext_vector_type(2)));
typedef float  f32x4  __attribute__((ext_vector_type(4)));

__device__ inline bf16x8 cvt8(const float* __restrict__ p) {
    float4 a = *(const float4*)p;
    float4 b = *(const float4*)(p + 4);
    bf16x8 r;
    r[0] = (__bf16)a.x; r[1] = (__bf16)a.y; r[2] = (__bf16)a.z; r[3] = (__bf16)a.w;
    r[4] = (__bf16)b.x; r[5] = (__bf16)b.y; r[6] = (__bf16)b.z; r[7] = (__bf16)b.w;
    return r;
}

// out[b,m] = 0.9*mlp_b[m] + 0.1*fk_b[m]
__global__ void init_out(const float* __restrict__ mlp_b,
                         const float* __restrict__ fk_b,
                         float* __restrict__ out) {
    int i = blockIdx.x * 256 + threadIdx.x;
    if (i < B_ * M_) {
        int m = i % M_;
        out[i] = 0.9f * mlp_b[m] + 0.1f * fk_b[m];
    }
}

// Pack A (f32 row-major) into MFMA fragment order, bf16:
// chunk c = ((ss*8 + bt)*4 + kf)*64 + lane  holds
// A[bt*16 + (lane&15)][ss*128 + kf*32 + (lane>>4)*8 .. +8).
// Writes fully coalesced 16B/lane; reads are 32B sub-segments of A rows.
__global__ void pack_a(const float* __restrict__ A, __bf16* __restrict__ Apk) {
    const int nchunk = SS_TOTAL * 8 * 4 * 64;   // 2,408,448 chunks of 8 elems
    for (int c = blockIdx.x * blockDim.x + threadIdx.x; c < nchunk;
         c += gridDim.x * blockDim.x) {
        int lane = c & 63;
        int kf   = (c >> 6) & 3;
        int bt   = (c >> 8) & 7;
        int ss   = c >> 11;
        int b = bt * 16 + (lane & 15);
        int k = ss * BK + kf * 32 + (lane >> 4) * 8;
        *(bf16x8*)(Apk + (size_t)c * 8) = cvt8(A + (size_t)b * KTOT + k);
    }
}

__global__ void event_pool(const float* __restrict__ SE,
                           const int* __restrict__ BE, int be_stride,
                           float* __restrict__ EP) {
    int b = blockIdx.x;
    int s1 = BE[(b*4 + 0) * be_stride];
    int e1 = BE[(b*4 + 1) * be_stride];
    int s2 = BE[(b*4 + 2) * be_stride];
    int e2 = BE[(b*4 + 3) * be_stride];
    float inv1 = 1.0f / (float)(e1 - s1);
    float inv2 = 1.0f / (float)(e2 - s2);
    for (int c = threadIdx.x; c < E_; c += 256) {
        float sum1 = 0.f, sum2 = 0.f;
        for (int s = s1; s < e1; ++s) sum1 += SE[((size_t)b * S_ + s) * E_ + c];
        for (int s = s2; s < e2; ++s) sum2 += SE[((size_t)b * S_ + s) * E_ + c];
        EP[b * (2*E_) + c]       = sum1 * inv1;
        EP[b * (2*E_) + E_ + c]  = sum2 * inv2;
    }
}

// out[b,m] += 0.9 * dot(EP[b,:], mlp_w[m,:])   K=1536, one wave per 16x16 tile
__global__ __launch_bounds__(256) void mlp_gemm(const float* __restrict__ EP,
                                                const float* __restrict__ Wm,
                                                float* __restrict__ out) {
    const int wid   = (blockIdx.x * 256 + threadIdx.x) >> 6;  // 0..383
    const int lane  = threadIdx.x & 63;
    const int bt    = wid & 7;    // b-tile 0..7
    const int mt    = wid >> 3;   // m-tile 0..47
    const int row16 = lane & 15;
    const int kgrp  = lane >> 4;
    const float* Arow = EP + (size_t)(bt*16 + row16) * (2*E_);
    const float* Brow = Wm + (size_t)(mt*16 + row16) * (2*E_);
    f32x4 acc = {};
    for (int k0 = 0; k0 < 2*E_; k0 += 32) {
        bf16x8 af = cvt8(Arow + k0 + kgrp*8);
        bf16x8 bv = cvt8(Brow + k0 + kgrp*8);
        acc = __builtin_amdgcn_mfma_f32_16x16x32_bf16(af, bv, acc, 0, 0, 0);
    }
    const int m = mt*16 + row16;
#pragma unroll
    for (int r = 0; r < 4; ++r) {
        const int b = bt*16 + kgrp*4 + r;
        out[b * M_ + m] += 0.9f * acc[r];  // unique writer per element in this kernel
    }
}

// partial[kz][b][m] = dot(A[b,kslice], W[m,kslice])
// 8 waves, tile 128b x 48m x 128k/superstep. Every global load is one
// contiguous segment: A register-direct from packed fragments (1KB/load),
// W staged via 512B-per-row float2 wave loads -> bf16 -> LDS (PITCH 272).
// Double-buffered LDS, depth-1 named-set prefetch, 1 barrier per superstep.
// 26.1 KB LDS/wg -> 4 wgs/CU (32 waves, full thread occupancy) so other
// workgroups' compute covers each wave's W-load latency at WRITE_W.

#define LOAD_A(AREG, sl)                                                      \
    _Pragma("unroll")                                                         \
    for (int kf = 0; kf < 4; ++kf)                                            \
        AREG[kf] = *(const bf16x8*)(abase + (size_t)(sl) * 16384 + kf * 512);

#define LOAD_W(sl)                                                            \
    _Pragma("unroll")                                                         \
    for (int i = 0; i < 6; ++i)                                               \
        wr[i] = *(const float2*)(wbase + (size_t)i * KTOT + (size_t)(sl) * BK);

#define WRITE_W(buf)                                                          \
    _Pragma("unroll")                                                         \
    for (int i = 0; i < 6; ++i) {                                             \
        bf16x2 h;                                                             \
        h[0] = (__bf16)wr[i].x; h[1] = (__bf16)wr[i].y;                       \
        *(bf16x2*)(&Wlds[buf][0] + wb + i * PITCH) = h;                       \
    }

#define COMPUTE(AREG, buf)                                                    \
    _Pragma("unroll")                                                         \
    for (int kf = 0; kf < 4; ++kf) {                                          \
        _Pragma("unroll")                                                     \
        for (int n = 0; n < 3; ++n) {                                         \
            bf16x8 wf = *(const bf16x8*)(&Wlds[buf][0] +                      \
                        (n * 16 + r16) * PITCH + kf * 64 + kg * 16);          \
            acc[n] = __builtin_amdgcn_mfma_f32_16x16x32_bf16(AREG[kf], wf,    \
                                                             acc[n], 0, 0, 0);\
        }                                                                     \
    }

__global__ __launch_bounds__(512, 4) void fk_gemm(const __bf16* __restrict__ Apk,
                                                  const float* __restrict__ W,
                                                  float* __restrict__ partial) {
    __shared__ __align__(16) char Wlds[2][BN * PITCH];  // 2 x 13,056 B

    const int wg = blockIdx.x;          // 0..671
    const int mt = wg % MTN;            // 0..15
    const int kz = wg / MTN;            // 0..41
    const int ss0 = kz * SS_PER;

    const int tid = threadIdx.x;
    const int wv  = tid >> 6;           // 0..7 = b-tile
    const int lane = tid & 63;
    const int r16 = lane & 15;
    const int kg  = lane >> 4;

    const float*  wbase = W + (size_t)(mt * BN + wv * 6) * KTOT
                            + (size_t)ss0 * BK + lane * 2;
    const int     wb    = (wv * 6) * PITCH + lane * 4;
    const __bf16* abase = Apk + ((size_t)ss0 * 8 + wv) * 2048 + lane * 8;

    f32x4 acc[3] = {};
    float2 wr[6];
    bf16x8 aA[4], aB[4];

    // prologue: stage ss-local 0 into buf 0
    LOAD_W(0)
    LOAD_A(aA, 0)
    WRITE_W(0)
    __syncthreads();

#pragma unroll 2
    for (int p = 0; p < SS_PER / 2; ++p) {
        // ss = 2p  (buf 0)
        LOAD_W(2 * p + 1)
        LOAD_A(aB, 2 * p + 1)
        COMPUTE(aA, 0)
        WRITE_W(1)
        __syncthreads();
        // ss = 2p+1  (buf 1)
        if (p < SS_PER / 2 - 1) {
            LOAD_W(2 * p + 2)
            LOAD_A(aA, 2 * p + 2)
        }
        COMPUTE(aB, 1)
        if (p < SS_PER / 2 - 1) {
            WRITE_W(0)
        }
        __syncthreads();
    }

    // D layout: col(lane&15) = m, row((lane>>4)*4 + r) = b   [m89/m91]
    float* pz = partial + (size_t)kz * (B_ * M_);
#pragma unroll
    for (int n = 0; n < 3; ++n) {
        const int m = mt * BN + n * 16 + r16;
#pragma unroll
        for (int r = 0; r < 4; ++r) {
            const int b = wv * 16 + kg * 4 + r;
            pz[(size_t)b * M_ + m] = acc[n][r];
        }
    }
}

// out[i] += 0.1 * sum_kz partial[kz][i], z split into ZC chunks via atomics
__global__ void reduce_k(const float* __restrict__ pp, float* __restrict__ out) {
    int t = blockIdx.x * 256 + threadIdx.x;
    int i = t % (B_ * M_);
    int zc = t / (B_ * M_);
    if (zc >= ZC) return;
    float s = 0.f;
#pragma unroll
    for (int z = zc * (KSPLIT / ZC); z < (zc + 1) * (KSPLIT / ZC); ++z)
        s += pp[(size_t)z * (B_ * M_) + i];
    atomicAdd(out + i, 0.1f * s);
}

extern "C" void kernel_launch(void* const* d_in, const int* in_sizes, int n_in,
                              void* d_out, int out_size, void* d_ws, size_t ws_size,
                              hipStream_t stream) {
    const float* se    = (const float*)d_in[0];
    const int*   be    = (const int*)  d_in[1];
    const float* mlp_w = (const float*)d_in[2];
    const float* mlp_b = (const float*)d_in[3];
    const float* fk_w  = (const float*)d_in[4];
    const float* fk_b  = (const float*)d_in[5];
    float* out = (float*)d_out;
    float* ep  = (float*)d_ws;                  // event_pair [128][1536] f32
    float* pp  = ep + (size_t)B_ * 2 * E_;      // partials [KSPLIT][128][768] f32
    __bf16* apk = (__bf16*)(pp + (size_t)KSPLIT * B_ * M_);  // packed A bf16

    const int be_stride = (in_sizes[1] == B_ * 4 * 2) ? 2 : 1;

    init_out<<<(B_ * M_ + 255) / 256, 256, 0, stream>>>(mlp_b, fk_b, out);
    pack_a<<<3072, 256, 0, stream>>>(se, apk);
    event_pool<<<B_, 256, 0, stream>>>(se, be, be_stride, ep);
    mlp_gemm<<<(B_ / 16) * (M_ / 16) / 4, 256, 0, stream>>>(ep, mlp_w, out);
    fk_gemm<<<MTN * KSPLIT, 512, 0, stream>>>(apk, fk_w, pp);
    reduce_k<<<(B_ * M_ * ZC + 255) / 256, 256, 0, stream>>>(pp, out);
}

// Round 10
// 172.867 us; speedup vs baseline: 1.1697x; 1.1697x over previous
//
#include <hip/hip_runtime.h>
#include <hip/hip_bf16.h>

#define B_ 128
#define S_ 196
#define E_ 768
#define M_ 768
#define KTOT (S_*E_)            // 150528
#define BK 256                  // k per superstep
#define SS_TOTAL (KTOT/BK)      // 588
#define KSPLIT 32
#define BN 48                   // m-rows per workgroup
#define MTN (M_/BN)             // 16
#define PITCH 528               // LDS row pitch bytes (16*odd -> uniform bank quads)
#define ZC 4                    // z-chunks in reduce

typedef __bf16 bf16x8 __attribute__((ext_vector_type(8)));
typedef __bf16 bf16x4 __attribute__((ext_vector_type(4)));
typedef float  f32x4  __attribute__((ext_vector_type(4)));

__device__ inline bf16x8 cvt8(const float* __restrict__ p) {
    float4 a = *(const float4*)p;
    float4 b = *(const float4*)(p + 4);
    bf16x8 r;
    r[0] = (__bf16)a.x; r[1] = (__bf16)a.y; r[2] = (__bf16)a.z; r[3] = (__bf16)a.w;
    r[4] = (__bf16)b.x; r[5] = (__bf16)b.y; r[6] = (__bf16)b.z; r[7] = (__bf16)b.w;
    return r;
}

// ---------------- prep: init_out | event_pool | pack_a (block-partitioned) ----
// blocks [0,384): out[b,m] = 0.9*mlp_b + 0.1*fk_b
// blocks [384,512): event_pool
// blocks [512,3584): pack A f32 -> bf16 MFMA-fragment order:
//   chunk c = ((ss*8 + bt)*8 + kf)*64 + lane  holds
//   A[bt*16 + (lane&15)][ss*256 + kf*32 + (lane>>4)*8 .. +8)
__global__ void prep(const float* __restrict__ mlp_b,
                     const float* __restrict__ fk_b,
                     const float* __restrict__ A,
                     const int* __restrict__ BE, int be_stride,
                     float* __restrict__ out,
                     float* __restrict__ EP,
                     __bf16* __restrict__ Apk) {
    const int bid = blockIdx.x;
    if (bid < 384) {
        int i = bid * 256 + threadIdx.x;
        int m = i % M_;
        out[i] = 0.9f * mlp_b[m] + 0.1f * fk_b[m];
    } else if (bid < 512) {
        int b = bid - 384;
        int s1 = BE[(b*4 + 0) * be_stride];
        int e1 = BE[(b*4 + 1) * be_stride];
        int s2 = BE[(b*4 + 2) * be_stride];
        int e2 = BE[(b*4 + 3) * be_stride];
        float inv1 = 1.0f / (float)(e1 - s1);
        float inv2 = 1.0f / (float)(e2 - s2);
        for (int c = threadIdx.x; c < E_; c += 256) {
            float sum1 = 0.f, sum2 = 0.f;
            for (int s = s1; s < e1; ++s) sum1 += A[((size_t)b * S_ + s) * E_ + c];
            for (int s = s2; s < e2; ++s) sum2 += A[((size_t)b * S_ + s) * E_ + c];
            EP[b * (2*E_) + c]       = sum1 * inv1;
            EP[b * (2*E_) + E_ + c]  = sum2 * inv2;
        }
    } else {
        const int nchunk = SS_TOTAL * 8 * 8 * 64;   // 2,408,448
        for (int c = (bid - 512) * 256 + threadIdx.x; c < nchunk; c += 3072 * 256) {
            int lane = c & 63;
            int kf   = (c >> 6) & 7;
            int bt   = (c >> 9) & 7;
            int ss   = c >> 12;
            int b = bt * 16 + (lane & 15);
            int k = ss * BK + kf * 32 + (lane >> 4) * 8;
            *(bf16x8*)(Apk + (size_t)c * 8) = cvt8(A + (size_t)b * KTOT + k);
        }
    }
}

// ---------------- fk_gemm: partial[kz][b][m] ------------------------------
// 8 waves, tile 128b x 48m x 256k/superstep. All global loads single-segment:
// A register-direct from packed frags (1KB/load, LLC-resident), W staged
// 1KB-per-row float4 wave loads -> bf16 -> LDS (PITCH 528 = 16*odd).
// 2-superstep-deep W register prefetch (w0/w1): each W load has a full
// superstep of latency slack before WRITE_W consumes it. Grid 512 = exactly
// 2 wgs/CU (VGPR<=128), proportional ss split (18-19 per kz).

#define LOAD_A(AREG, sl)                                                      \
    _Pragma("unroll")                                                         \
    for (int kf = 0; kf < 8; ++kf)                                            \
        AREG[kf] = *(const bf16x8*)(abase + (size_t)(sl) * 32768 + kf * 512);

#define LOAD_W(WREG, sl)                                                      \
    _Pragma("unroll")                                                         \
    for (int i = 0; i < 6; ++i)                                               \
        WREG[i] = *(const float4*)(wbase + (size_t)i * KTOT + (size_t)(sl) * BK);

#define WRITE_W(WREG, buf)                                                    \
    _Pragma("unroll")                                                         \
    for (int i = 0; i < 6; ++i) {                                             \
        bf16x4 h;                                                             \
        h[0] = (__bf16)WREG[i].x; h[1] = (__bf16)WREG[i].y;                   \
        h[2] = (__bf16)WREG[i].z; h[3] = (__bf16)WREG[i].w;                   \
        *(bf16x4*)(&Wlds[buf][0] + wb + i * PITCH) = h;                       \
    }

#define COMPUTE(AREG, buf)                                                    \
    _Pragma("unroll")                                                         \
    for (int kf = 0; kf < 8; ++kf) {                                          \
        _Pragma("unroll")                                                     \
        for (int n = 0; n < 3; ++n) {                                         \
            bf16x8 wf = *(const bf16x8*)(&Wlds[buf][0] +                      \
                        (n * 16 + r16) * PITCH + kf * 64 + kg * 16);          \
            acc[n] = __builtin_amdgcn_mfma_f32_16x16x32_bf16(AREG[kf], wf,    \
                                                             acc[n], 0, 0, 0);\
        }                                                                     \
    }

__global__ __launch_bounds__(512, 4) void fk_gemm(const __bf16* __restrict__ Apk,
                                                  const float* __restrict__ W,
                                                  float* __restrict__ partial) {
    __shared__ __align__(16) char Wlds[2][BN * PITCH];  // 2 x 25,344 B

    const int wg = blockIdx.x;          // 0..511
    const int mt = wg & (MTN - 1);      // 0..15
    const int kz = wg >> 4;             // 0..31
    const int ss0 = (SS_TOTAL * kz) / KSPLIT;
    const int SSN = (SS_TOTAL * (kz + 1)) / KSPLIT - ss0;   // 18 or 19

    const int tid = threadIdx.x;
    const int wv  = tid >> 6;           // 0..7 = b-tile
    const int lane = tid & 63;
    const int r16 = lane & 15;
    const int kg  = lane >> 4;

    const float*  wbase = W + (size_t)(mt * BN + wv * 6) * KTOT
                            + (size_t)ss0 * BK + lane * 4;
    const int     wb    = (wv * 6) * PITCH + lane * 8;
    const __bf16* abase = Apk + ((size_t)ss0 * 8 + wv) * 4096 + lane * 8;

    f32x4 acc[3] = {};
    float4 w0[6], w1[6];
    bf16x8 aA[8];

    // prologue: stage ss 0 into buf 0; w1 <- W(1) in flight
    LOAD_W(w0, 0)
    WRITE_W(w0, 0)
    LOAD_W(w1, 1)
    __syncthreads();

    int sl = 0;
    for (; sl + 2 < SSN; sl += 2) {
        // even: buf0 ready W(sl)
        LOAD_A(aA, sl)
        LOAD_W(w0, sl + 2)
        COMPUTE(aA, 0)
        WRITE_W(w1, 1)                  // W(sl+1), loaded a full ss ago
        __syncthreads();
        // odd: buf1 ready W(sl+1)
        LOAD_A(aA, sl + 1)
        if (sl + 3 < SSN) { LOAD_W(w1, sl + 3) }
        COMPUTE(aA, 1)
        WRITE_W(w0, 0)                  // W(sl+2)
        __syncthreads();
    }
    // tail: remaining r = SSN - sl in {1, 2}
    LOAD_A(aA, sl)
    COMPUTE(aA, 0)
    if (SSN - sl == 2) {
        WRITE_W(w1, 1)
        __syncthreads();
        LOAD_A(aA, sl + 1)
        COMPUTE(aA, 1)
    }

    // D layout: col(lane&15) = m, row((lane>>4)*4 + r) = b   [m89/m91]
    float* pz = partial + (size_t)kz * (B_ * M_);
#pragma unroll
    for (int n = 0; n < 3; ++n) {
        const int m = mt * BN + n * 16 + r16;
#pragma unroll
        for (int r = 0; r < 4; ++r) {
            const int b = wv * 16 + kg * 4 + r;
            pz[(size_t)b * M_ + m] = acc[n][r];
        }
    }
}

// ---------------- post: reduce_k | mlp_gemm (block-partitioned) -------------
// blocks [0,1536): out[i] += 0.1 * sum_z pp[z][i]  (ZC=4 chunks of 8, atomic)
// blocks [1536,1632): out[b,m] += 0.9 * dot(EP[b,:], mlp_w[m,:]) (atomic)
__global__ __launch_bounds__(256) void post(const float* __restrict__ pp,
                                            const float* __restrict__ EP,
                                            const float* __restrict__ Wm,
                                            float* __restrict__ out) {
    const int bid = blockIdx.x;
    if (bid < 1536) {
        int t = bid * 256 + threadIdx.x;
        int i = t % (B_ * M_);
        int zc = t / (B_ * M_);
        float s = 0.f;
#pragma unroll
        for (int z = zc * (KSPLIT / ZC); z < (zc + 1) * (KSPLIT / ZC); ++z)
            s += pp[(size_t)z * (B_ * M_) + i];
        atomicAdd(out + i, 0.1f * s);
    } else {
        const int wid   = ((bid - 1536) * 256 + threadIdx.x) >> 6;  // 0..383
        const int lane  = threadIdx.x & 63;
        const int bt    = wid & 7;
        const int mt    = wid >> 3;
        const int row16 = lane & 15;
        const int kgrp  = lane >> 4;
        const float* Arow = EP + (size_t)(bt*16 + row16) * (2*E_);
        const float* Brow = Wm + (size_t)(mt*16 + row16) * (2*E_);
        f32x4 acc = {};
        for (int k0 = 0; k0 < 2*E_; k0 += 32) {
            bf16x8 af = cvt8(Arow + k0 + kgrp*8);
            bf16x8 bv = cvt8(Brow + k0 + kgrp*8);
            acc = __builtin_amdgcn_mfma_f32_16x16x32_bf16(af, bv, acc, 0, 0, 0);
        }
        const int m = mt*16 + row16;
#pragma unroll
        for (int r = 0; r < 4; ++r) {
            const int b = bt*16 + kgrp*4 + r;
            atomicAdd(out + b * M_ + m, 0.9f * acc[r]);
        }
    }
}

extern "C" void kernel_launch(void* const* d_in, const int* in_sizes, int n_in,
                              void* d_out, int out_size, void* d_ws, size_t ws_size,
                              hipStream_t stream) {
    const float* se    = (const float*)d_in[0];
    const int*   be    = (const int*)  d_in[1];
    const float* mlp_w = (const float*)d_in[2];
    const float* mlp_b = (const float*)d_in[3];
    const float* fk_w  = (const float*)d_in[4];
    const float* fk_b  = (const float*)d_in[5];
    float* out = (float*)d_out;
    float* ep  = (float*)d_ws;                  // event_pair [128][1536] f32
    float* pp  = ep + (size_t)B_ * 2 * E_;      // partials [KSPLIT][128][768] f32
    __bf16* apk = (__bf16*)(pp + (size_t)KSPLIT * B_ * M_);  // packed A bf16

    const int be_stride = (in_sizes[1] == B_ * 4 * 2) ? 2 : 1;

    prep<<<3584, 256, 0, stream>>>(mlp_b, fk_b, se, be, be_stride, out, ep, apk);
    fk_gemm<<<MTN * KSPLIT, 512, 0, stream>>>(apk, fk_w, pp);
    post<<<1632, 256, 0, stream>>>(pp, ep, mlp_w, out);
}

// Round 11
// 172.484 us; speedup vs baseline: 1.1723x; 1.0022x over previous
//
#include <hip/hip_runtime.h>
#include <hip/hip_bf16.h>

#define B_ 128
#define S_ 196
#define E_ 768
#define M_ 768
#define KTOT (S_*E_)            // 150528
#define BK 256                  // k per superstep
#define SS_TOTAL (KTOT/BK)      // 588
#define KSPLIT 32
#define BN 48                   // m-rows per workgroup
#define MTN (M_/BN)             // 16
#define PITCH 528               // LDS row pitch bytes (16*odd -> uniform bank quads)
#define ZC 4                    // z-chunks in reduce

typedef __bf16 bf16x8 __attribute__((ext_vector_type(8)));
typedef __bf16 bf16x4 __attribute__((ext_vector_type(4)));
typedef float  f32x4  __attribute__((ext_vector_type(4)));

__device__ inline bf16x8 cvt8(const float* __restrict__ p) {
    float4 a = *(const float4*)p;
    float4 b = *(const float4*)(p + 4);
    bf16x8 r;
    r[0] = (__bf16)a.x; r[1] = (__bf16)a.y; r[2] = (__bf16)a.z; r[3] = (__bf16)a.w;
    r[4] = (__bf16)b.x; r[5] = (__bf16)b.y; r[6] = (__bf16)b.z; r[7] = (__bf16)b.w;
    return r;
}

// ---------------- prep: init_out | event_pool | pack_a (block-partitioned) ----
__global__ void prep(const float* __restrict__ mlp_b,
                     const float* __restrict__ fk_b,
                     const float* __restrict__ A,
                     const int* __restrict__ BE, int be_stride,
                     float* __restrict__ out,
                     float* __restrict__ EP,
                     __bf16* __restrict__ Apk) {
    const int bid = blockIdx.x;
    if (bid < 384) {
        int i = bid * 256 + threadIdx.x;
        int m = i % M_;
        out[i] = 0.9f * mlp_b[m] + 0.1f * fk_b[m];
    } else if (bid < 512) {
        int b = bid - 384;
        int s1 = BE[(b*4 + 0) * be_stride];
        int e1 = BE[(b*4 + 1) * be_stride];
        int s2 = BE[(b*4 + 2) * be_stride];
        int e2 = BE[(b*4 + 3) * be_stride];
        float inv1 = 1.0f / (float)(e1 - s1);
        float inv2 = 1.0f / (float)(e2 - s2);
        for (int c = threadIdx.x; c < E_; c += 256) {
            float sum1 = 0.f, sum2 = 0.f;
            for (int s = s1; s < e1; ++s) sum1 += A[((size_t)b * S_ + s) * E_ + c];
            for (int s = s2; s < e2; ++s) sum2 += A[((size_t)b * S_ + s) * E_ + c];
            EP[b * (2*E_) + c]       = sum1 * inv1;
            EP[b * (2*E_) + E_ + c]  = sum2 * inv2;
        }
    } else {
        const int nchunk = SS_TOTAL * 8 * 8 * 64;   // 2,408,448
        for (int c = (bid - 512) * 256 + threadIdx.x; c < nchunk; c += 3072 * 256) {
            int lane = c & 63;
            int kf   = (c >> 6) & 7;
            int bt   = (c >> 9) & 7;
            int ss   = c >> 12;
            int b = bt * 16 + (lane & 15);
            int k = ss * BK + kf * 32 + (lane >> 4) * 8;
            *(bf16x8*)(Apk + (size_t)c * 8) = cvt8(A + (size_t)b * KTOT + k);
        }
    }
}

// ---------------- fk_gemm: partial[kz][b][m] ------------------------------
// 8 waves, tile 128b x 48m x 256k/superstep. All global loads single-segment.
// W: depth-1 register prefetch (load ss n, LDS-write in ss n+1).
// A: depth-1 named-set prefetch (aA/aB) so the L2/LLC latency of the packed-A
// fragment loads is covered by a full superstep instead of being consumed in
// the phase it's issued. VGPR ~115 -> 4 waves/SIMD at 512 threads, 2 wgs/CU.

#define LOAD_A(AREG, sl)                                                      \
    _Pragma("unroll")                                                         \
    for (int kf = 0; kf < 8; ++kf)                                            \
        AREG[kf] = *(const bf16x8*)(abase + (size_t)(sl) * 32768 + kf * 512);

#define LOAD_W(sl)                                                            \
    _Pragma("unroll")                                                         \
    for (int i = 0; i < 6; ++i)                                               \
        w[i] = *(const float4*)(wbase + (size_t)i * KTOT + (size_t)(sl) * BK);

#define WRITE_W(buf)                                                          \
    _Pragma("unroll")                                                         \
    for (int i = 0; i < 6; ++i) {                                             \
        bf16x4 h;                                                             \
        h[0] = (__bf16)w[i].x; h[1] = (__bf16)w[i].y;                         \
        h[2] = (__bf16)w[i].z; h[3] = (__bf16)w[i].w;                         \
        *(bf16x4*)(&Wlds[buf][0] + wb + i * PITCH) = h;                       \
    }

#define COMPUTE(AREG, buf)                                                    \
    _Pragma("unroll")                                                         \
    for (int kf = 0; kf < 8; ++kf) {                                          \
        _Pragma("unroll")                                                     \
        for (int n = 0; n < 3; ++n) {                                         \
            bf16x8 wf = *(const bf16x8*)(&Wlds[buf][0] +                      \
                        (n * 16 + r16) * PITCH + kf * 64 + kg * 16);          \
            acc[n] = __builtin_amdgcn_mfma_f32_16x16x32_bf16(AREG[kf], wf,    \
                                                             acc[n], 0, 0, 0);\
        }                                                                     \
    }

__global__ __launch_bounds__(512, 4) void fk_gemm(const __bf16* __restrict__ Apk,
                                                  const float* __restrict__ W,
                                                  float* __restrict__ partial) {
    __shared__ __align__(16) char Wlds[2][BN * PITCH];  // 2 x 25,344 B

    const int wg = blockIdx.x;          // 0..511
    const int mt = wg & (MTN - 1);      // 0..15
    const int kz = wg >> 4;             // 0..31
    const int ss0 = (SS_TOTAL * kz) / KSPLIT;
    const int SSN = (SS_TOTAL * (kz + 1)) / KSPLIT - ss0;   // 18 or 19

    const int tid = threadIdx.x;
    const int wv  = tid >> 6;           // 0..7 = b-tile
    const int lane = tid & 63;
    const int r16 = lane & 15;
    const int kg  = lane >> 4;

    const float*  wbase = W + (size_t)(mt * BN + wv * 6) * KTOT
                            + (size_t)ss0 * BK + lane * 4;
    const int     wb    = (wv * 6) * PITCH + lane * 8;
    const __bf16* abase = Apk + ((size_t)ss0 * 8 + wv) * 4096 + lane * 8;

    f32x4 acc[3] = {};
    float4 w[6];
    bf16x8 aA[8], aB[8];

    // prologue: stage ss0 into buf0; preload A(0); W(1) in flight
    LOAD_W(0)
    WRITE_W(0)
    LOAD_A(aA, 0)
    LOAD_W(1)
    __syncthreads();

    int sl = 0;
    for (; sl + 1 < SSN; sl += 2) {
        // even: compute ss sl from buf0; stage W(sl+1) -> buf1
        LOAD_A(aB, sl + 1)
        COMPUTE(aA, 0)
        WRITE_W(1)                      // W(sl+1), loaded ~1 ss ago
        const bool more2 = (sl + 2 < SSN);
        if (more2) { LOAD_W(sl + 2) }
        __syncthreads();
        // odd: compute ss sl+1 from buf1; stage W(sl+2) -> buf0
        if (more2) { LOAD_A(aA, sl + 2) }
        COMPUTE(aB, 1)
        if (more2) {
            WRITE_W(0)                  // W(sl+2), loaded ~1 ss ago
            if (sl + 3 < SSN) { LOAD_W(sl + 3) }
            __syncthreads();
        }
    }
    if (SSN & 1) {  // leftover even ss in buf0 with aA preloaded
        COMPUTE(aA, 0)
    }

    // D layout: col(lane&15) = m, row((lane>>4)*4 + r) = b   [m89/m91]
    float* pz = partial + (size_t)kz * (B_ * M_);
#pragma unroll
    for (int n = 0; n < 3; ++n) {
        const int m = mt * BN + n * 16 + r16;
#pragma unroll
        for (int r = 0; r < 4; ++r) {
            const int b = wv * 16 + kg * 4 + r;
            pz[(size_t)b * M_ + m] = acc[n][r];
        }
    }
}

// ---------------- post: reduce_k | mlp_gemm (block-partitioned) -------------
__global__ __launch_bounds__(256) void post(const float* __restrict__ pp,
                                            const float* __restrict__ EP,
                                            const float* __restrict__ Wm,
                                            float* __restrict__ out) {
    const int bid = blockIdx.x;
    if (bid < 1536) {
        int t = bid * 256 + threadIdx.x;
        int i = t % (B_ * M_);
        int zc = t / (B_ * M_);
        float s = 0.f;
#pragma unroll
        for (int z = zc * (KSPLIT / ZC); z < (zc + 1) * (KSPLIT / ZC); ++z)
            s += pp[(size_t)z * (B_ * M_) + i];
        atomicAdd(out + i, 0.1f * s);
    } else {
        const int wid   = ((bid - 1536) * 256 + threadIdx.x) >> 6;  // 0..383
        const int lane  = threadIdx.x & 63;
        const int bt    = wid & 7;
        const int mt    = wid >> 3;
        const int row16 = lane & 15;
        const int kgrp  = lane >> 4;
        const float* Arow = EP + (size_t)(bt*16 + row16) * (2*E_);
        const float* Brow = Wm + (size_t)(mt*16 + row16) * (2*E_);
        f32x4 acc = {};
        for (int k0 = 0; k0 < 2*E_; k0 += 32) {
            bf16x8 af = cvt8(Arow + k0 + kgrp*8);
            bf16x8 bv = cvt8(Brow + k0 + kgrp*8);
            acc = __builtin_amdgcn_mfma_f32_16x16x32_bf16(af, bv, acc, 0, 0, 0);
        }
        const int m = mt*16 + row16;
#pragma unroll
        for (int r = 0; r < 4; ++r) {
            const int b = bt*16 + kgrp*4 + r;
            atomicAdd(out + b * M_ + m, 0.9f * acc[r]);
        }
    }
}

extern "C" void kernel_launch(void* const* d_in, const int* in_sizes, int n_in,
                              void* d_out, int out_size, void* d_ws, size_t ws_size,
                              hipStream_t stream) {
    const float* se    = (const float*)d_in[0];
    const int*   be    = (const int*)  d_in[1];
    const float* mlp_w = (const float*)d_in[2];
    const float* mlp_b = (const float*)d_in[3];
    const float* fk_w  = (const float*)d_in[4];
    const float* fk_b  = (const float*)d_in[5];
    float* out = (float*)d_out;
    float* ep  = (float*)d_ws;                  // event_pair [128][1536] f32
    float* pp  = ep + (size_t)B_ * 2 * E_;      // partials [KSPLIT][128][768] f32
    __bf16* apk = (__bf16*)(pp + (size_t)KSPLIT * B_ * M_);  // packed A bf16

    const int be_stride = (in_sizes[1] == B_ * 4 * 2) ? 2 : 1;

    prep<<<3584, 256, 0, stream>>>(mlp_b, fk_b, se, be, be_stride, out, ep, apk);
    fk_gemm<<<MTN * KSPLIT, 512, 0, stream>>>(apk, fk_w, pp);
    post<<<1632, 256, 0, stream>>>(pp, ep, mlp_w, out);
}

// Round 12
// 171.820 us; speedup vs baseline: 1.1768x; 1.0039x over previous
//
#include <hip/hip_runtime.h>
#include <hip/hip_bf16.h>

#define B_ 128
#define S_ 196
#define E_ 768
#define M_ 768
#define KTOT (S_*E_)            // 150528
#define BK 256                  // k per superstep
#define SS_TOTAL (KTOT/BK)      // 588
#define KSPLIT 32
#define BN 48                   // m-rows per workgroup
#define MTN (M_/BN)             // 16
#define PITCH 528               // LDS row pitch bytes (16*odd -> uniform bank quads)
#define ZC 4                    // z-chunks in reduce

typedef __bf16 bf16x8 __attribute__((ext_vector_type(8)));
typedef __bf16 bf16x4 __attribute__((ext_vector_type(4)));
typedef float  f32x4  __attribute__((ext_vector_type(4)));

__device__ inline bf16x8 cvt8(const float* __restrict__ p) {
    float4 a = *(const float4*)p;
    float4 b = *(const float4*)(p + 4);
    bf16x8 r;
    r[0] = (__bf16)a.x; r[1] = (__bf16)a.y; r[2] = (__bf16)a.z; r[3] = (__bf16)a.w;
    r[4] = (__bf16)b.x; r[5] = (__bf16)b.y; r[6] = (__bf16)b.z; r[7] = (__bf16)b.w;
    return r;
}

// Barrier WITHOUT the implicit vmcnt(0) drain __syncthreads() carries.
// lgkmcnt(0) makes this wave's ds_write/ds_read complete (the only cross-wave
// hazard is through LDS); global loads into private registers stay in flight
// across the barrier (T4 counted-vmcnt: compiler still emits dependence-driven
// vmcnt(N) waits where w[]/aA/aB are consumed).
__device__ inline void barrier_nodrain() {
    asm volatile("s_waitcnt lgkmcnt(0)" ::: "memory");
    __builtin_amdgcn_s_barrier();
}

// ---------------- prep: init_out | event_pool | pack_a (block-partitioned) ----
__global__ void prep(const float* __restrict__ mlp_b,
                     const float* __restrict__ fk_b,
                     const float* __restrict__ A,
                     const int* __restrict__ BE, int be_stride,
                     float* __restrict__ out,
                     float* __restrict__ EP,
                     __bf16* __restrict__ Apk) {
    const int bid = blockIdx.x;
    if (bid < 384) {
        int i = bid * 256 + threadIdx.x;
        int m = i % M_;
        out[i] = 0.9f * mlp_b[m] + 0.1f * fk_b[m];
    } else if (bid < 512) {
        int b = bid - 384;
        int s1 = BE[(b*4 + 0) * be_stride];
        int e1 = BE[(b*4 + 1) * be_stride];
        int s2 = BE[(b*4 + 2) * be_stride];
        int e2 = BE[(b*4 + 3) * be_stride];
        float inv1 = 1.0f / (float)(e1 - s1);
        float inv2 = 1.0f / (float)(e2 - s2);
        for (int c = threadIdx.x; c < E_; c += 256) {
            float sum1 = 0.f, sum2 = 0.f;
            for (int s = s1; s < e1; ++s) sum1 += A[((size_t)b * S_ + s) * E_ + c];
            for (int s = s2; s < e2; ++s) sum2 += A[((size_t)b * S_ + s) * E_ + c];
            EP[b * (2*E_) + c]       = sum1 * inv1;
            EP[b * (2*E_) + E_ + c]  = sum2 * inv2;
        }
    } else {
        const int nchunk = SS_TOTAL * 8 * 8 * 64;   // 2,408,448
        for (int c = (bid - 512) * 256 + threadIdx.x; c < nchunk; c += 3072 * 256) {
            int lane = c & 63;
            int kf   = (c >> 6) & 7;
            int bt   = (c >> 9) & 7;
            int ss   = c >> 12;
            int b = bt * 16 + (lane & 15);
            int k = ss * BK + kf * 32 + (lane >> 4) * 8;
            *(bf16x8*)(Apk + (size_t)c * 8) = cvt8(A + (size_t)b * KTOT + k);
        }
    }
}

// ---------------- fk_gemm: partial[kz][b][m] ------------------------------
// 8 waves, tile 128b x 48m x 256k/superstep. All global loads single-segment.
// W: depth-1 register prefetch (load ss n, LDS-write in ss n+1).
// A: depth-1 named-set prefetch (aA/aB). Barriers are raw s_barrier +
// lgkmcnt(0) only -- no vmcnt(0) drain, so prefetched loads survive phase
// boundaries (the m97 barrier-drain stall removed).

#define LOAD_A(AREG, sl)                                                      \
    _Pragma("unroll")                                                         \
    for (int kf = 0; kf < 8; ++kf)                                            \
        AREG[kf] = *(const bf16x8*)(abase + (size_t)(sl) * 32768 + kf * 512);

#define LOAD_W(sl)                                                            \
    _Pragma("unroll")                                                         \
    for (int i = 0; i < 6; ++i)                                               \
        w[i] = *(const float4*)(wbase + (size_t)i * KTOT + (size_t)(sl) * BK);

#define WRITE_W(buf)                                                          \
    _Pragma("unroll")                                                         \
    for (int i = 0; i < 6; ++i) {                                             \
        bf16x4 h;                                                             \
        h[0] = (__bf16)w[i].x; h[1] = (__bf16)w[i].y;                         \
        h[2] = (__bf16)w[i].z; h[3] = (__bf16)w[i].w;                         \
        *(bf16x4*)(&Wlds[buf][0] + wb + i * PITCH) = h;                       \
    }

#define COMPUTE(AREG, buf)                                                    \
    _Pragma("unroll")                                                         \
    for (int kf = 0; kf < 8; ++kf) {                                          \
        _Pragma("unroll")                                                     \
        for (int n = 0; n < 3; ++n) {                                         \
            bf16x8 wf = *(const bf16x8*)(&Wlds[buf][0] +                      \
                        (n * 16 + r16) * PITCH + kf * 64 + kg * 16);          \
            acc[n] = __builtin_amdgcn_mfma_f32_16x16x32_bf16(AREG[kf], wf,    \
                                                             acc[n], 0, 0, 0);\
        }                                                                     \
    }

__global__ __launch_bounds__(512, 4) void fk_gemm(const __bf16* __restrict__ Apk,
                                                  const float* __restrict__ W,
                                                  float* __restrict__ partial) {
    __shared__ __align__(16) char Wlds[2][BN * PITCH];  // 2 x 25,344 B

    const int wg = blockIdx.x;          // 0..511
    const int mt = wg & (MTN - 1);      // 0..15
    const int kz = wg >> 4;             // 0..31
    const int ss0 = (SS_TOTAL * kz) / KSPLIT;
    const int SSN = (SS_TOTAL * (kz + 1)) / KSPLIT - ss0;   // 18 or 19

    const int tid = threadIdx.x;
    const int wv  = tid >> 6;           // 0..7 = b-tile
    const int lane = tid & 63;
    const int r16 = lane & 15;
    const int kg  = lane >> 4;

    const float*  wbase = W + (size_t)(mt * BN + wv * 6) * KTOT
                            + (size_t)ss0 * BK + lane * 4;
    const int     wb    = (wv * 6) * PITCH + lane * 8;
    const __bf16* abase = Apk + ((size_t)ss0 * 8 + wv) * 4096 + lane * 8;

    f32x4 acc[3] = {};
    float4 w[6];
    bf16x8 aA[8], aB[8];

    // prologue: stage ss0 into buf0; preload A(0); W(1) in flight
    LOAD_W(0)
    WRITE_W(0)
    LOAD_A(aA, 0)
    LOAD_W(1)
    barrier_nodrain();

    int sl = 0;
    for (; sl + 1 < SSN; sl += 2) {
        // even: compute ss sl from buf0; stage W(sl+1) -> buf1
        LOAD_A(aB, sl + 1)
        COMPUTE(aA, 0)
        WRITE_W(1)                      // W(sl+1), loaded ~1 ss ago
        const bool more2 = (sl + 2 < SSN);
        if (more2) { LOAD_W(sl + 2) }
        barrier_nodrain();
        // odd: compute ss sl+1 from buf1; stage W(sl+2) -> buf0
        if (more2) { LOAD_A(aA, sl + 2) }
        COMPUTE(aB, 1)
        if (more2) {
            WRITE_W(0)                  // W(sl+2), loaded ~1 ss ago
            if (sl + 3 < SSN) { LOAD_W(sl + 3) }
            barrier_nodrain();
        }
    }
    if (SSN & 1) {  // leftover even ss in buf0 with aA preloaded
        COMPUTE(aA, 0)
    }

    // D layout: col(lane&15) = m, row((lane>>4)*4 + r) = b   [m89/m91]
    float* pz = partial + (size_t)kz * (B_ * M_);
#pragma unroll
    for (int n = 0; n < 3; ++n) {
        const int m = mt * BN + n * 16 + r16;
#pragma unroll
        for (int r = 0; r < 4; ++r) {
            const int b = wv * 16 + kg * 4 + r;
            pz[(size_t)b * M_ + m] = acc[n][r];
        }
    }
}

// ---------------- post: reduce_k | mlp_gemm (block-partitioned) -------------
__global__ __launch_bounds__(256) void post(const float* __restrict__ pp,
                                            const float* __restrict__ EP,
                                            const float* __restrict__ Wm,
                                            float* __restrict__ out) {
    const int bid = blockIdx.x;
    if (bid < 1536) {
        int t = bid * 256 + threadIdx.x;
        int i = t % (B_ * M_);
        int zc = t / (B_ * M_);
        float s = 0.f;
#pragma unroll
        for (int z = zc * (KSPLIT / ZC); z < (zc + 1) * (KSPLIT / ZC); ++z)
            s += pp[(size_t)z * (B_ * M_) + i];
        atomicAdd(out + i, 0.1f * s);
    } else {
        const int wid   = ((bid - 1536) * 256 + threadIdx.x) >> 6;  // 0..383
        const int lane  = threadIdx.x & 63;
        const int bt    = wid & 7;
        const int mt    = wid >> 3;
        const int row16 = lane & 15;
        const int kgrp  = lane >> 4;
        const float* Arow = EP + (size_t)(bt*16 + row16) * (2*E_);
        const float* Brow = Wm + (size_t)(mt*16 + row16) * (2*E_);
        f32x4 acc = {};
        for (int k0 = 0; k0 < 2*E_; k0 += 32) {
            bf16x8 af = cvt8(Arow + k0 + kgrp*8);
            bf16x8 bv = cvt8(Brow + k0 + kgrp*8);
            acc = __builtin_amdgcn_mfma_f32_16x16x32_bf16(af, bv, acc, 0, 0, 0);
        }
        const int m = mt*16 + row16;
#pragma unroll
        for (int r = 0; r < 4; ++r) {
            const int b = bt*16 + kgrp*4 + r;
            atomicAdd(out + b * M_ + m, 0.9f * acc[r]);
        }
    }
}

extern "C" void kernel_launch(void* const* d_in, const int* in_sizes, int n_in,
                              void* d_out, int out_size, void* d_ws, size_t ws_size,
                              hipStream_t stream) {
    const float* se    = (const float*)d_in[0];
    const int*   be    = (const int*)  d_in[1];
    const float* mlp_w = (const float*)d_in[2];
    const float* mlp_b = (const float*)d_in[3];
    const float* fk_w  = (const float*)d_in[4];
    const float* fk_b  = (const float*)d_in[5];
    float* out = (float*)d_out;
    float* ep  = (float*)d_ws;                  // event_pair [128][1536] f32
    float* pp  = ep + (size_t)B_ * 2 * E_;      // partials [KSPLIT][128][768] f32
    __bf16* apk = (__bf16*)(pp + (size_t)KSPLIT * B_ * M_);  // packed A bf16

    const int be_stride = (in_sizes[1] == B_ * 4 * 2) ? 2 : 1;

    prep<<<3584, 256, 0, stream>>>(mlp_b, fk_b, se, be, be_stride, out, ep, apk);
    fk_gemm<<<MTN * KSPLIT, 512, 0, stream>>>(apk, fk_w, pp);
    post<<<1632, 256, 0, stream>>>(pp, ep, mlp_w, out);
}